// Round 1
// baseline (409.891 us; speedup 1.0000x reference)
//
#include <hip/hip_runtime.h>

typedef __attribute__((ext_vector_type(8))) short short8;
typedef __attribute__((ext_vector_type(4))) float f32x4;

#define S_LEN 4096
#define C_DIM 512
#define NH 8
#define HD 64
#define NG 32
#define GS 16
#define B_DIM 2

__device__ __forceinline__ unsigned short f2bf(float f) {
  union { float f; unsigned int u; } v; v.f = f;
  unsigned int r = v.u + 0x7fffu + ((v.u >> 16) & 1u);
  return (unsigned short)(r >> 16);
}

// ---------------- GroupNorm stats: one block per (b, group) ----------------
__global__ __launch_bounds__(256) void gn_stats_kernel(const float* __restrict__ x,
                                                       float* __restrict__ stats) {
  int bg = blockIdx.x;            // 0..63
  int b = bg >> 5, g = bg & 31;
  const float* xp = x + (size_t)b * S_LEN * C_DIM + g * GS;
  float s1 = 0.f, s2 = 0.f;
  for (int i = threadIdx.x; i < S_LEN * 4; i += 256) {
    int s = i >> 2, c4 = i & 3;
    float4 v = *(const float4*)&xp[(size_t)s * C_DIM + c4 * 4];
    s1 += v.x + v.y + v.z + v.w;
    s2 += v.x * v.x + v.y * v.y + v.z * v.z + v.w * v.w;
  }
  for (int off = 1; off < 64; off <<= 1) {
    s1 += __shfl_xor(s1, off);
    s2 += __shfl_xor(s2, off);
  }
  __shared__ float r1[4], r2[4];
  int w = threadIdx.x >> 6;
  if ((threadIdx.x & 63) == 0) { r1[w] = s1; r2[w] = s2; }
  __syncthreads();
  if (threadIdx.x == 0) {
    float a = r1[0] + r1[1] + r1[2] + r1[3];
    float q = r2[0] + r2[1] + r2[2] + r2[3];
    const float invN = 1.0f / (float)(S_LEN * GS);
    float mean = a * invN;
    float var = q * invN - mean * mean;
    stats[bg * 2] = mean;
    stats[bg * 2 + 1] = rsqrtf(var + 1e-6f);
  }
}

// ---------------- GroupNorm apply + bf16 cast ----------------
__global__ __launch_bounds__(256) void gn_apply_kernel(const float* __restrict__ x,
                                                       const float* __restrict__ stats,
                                                       const float* __restrict__ scale,
                                                       const float* __restrict__ bias,
                                                       unsigned short* __restrict__ out) {
  int idx = blockIdx.x * 256 + threadIdx.x;   // over total/4 = 1048576
  int e = idx * 4;
  int c = e & (C_DIM - 1);
  int bs = e >> 9;
  int b = bs >> 12;
  int grp = b * NG + (c >> 4);
  float mean = stats[grp * 2], rstd = stats[grp * 2 + 1];
  float4 v = *(const float4*)&x[e];
  ushort4 o;
  o.x = f2bf((v.x - mean) * rstd * scale[c]     + bias[c]);
  o.y = f2bf((v.y - mean) * rstd * scale[c + 1] + bias[c + 1]);
  o.z = f2bf((v.z - mean) * rstd * scale[c + 2] + bias[c + 2]);
  o.w = f2bf((v.w - mean) * rstd * scale[c + 3] + bias[c + 3]);
  *(ushort4*)&out[e] = o;
}

// ---------------- weight transpose [K][N] f32 -> [N][K] bf16 ----------------
__global__ __launch_bounds__(256) void transpose_bf16_kernel(const float* __restrict__ src,
                                                             unsigned short* __restrict__ dst,
                                                             int K, int N) {
  __shared__ float tile[32][33];
  int n0 = blockIdx.x * 32, k0 = blockIdx.y * 32;
  int c = threadIdx.x & 31, r0 = threadIdx.x >> 5;
  for (int i = 0; i < 4; ++i) {
    int r = r0 + i * 8;
    tile[r][c] = src[(size_t)(k0 + r) * N + n0 + c];
  }
  __syncthreads();
  for (int i = 0; i < 4; ++i) {
    int r = r0 + i * 8;
    dst[(size_t)(n0 + r) * K + k0 + c] = f2bf(tile[c][r]);
  }
}

// ---------------- bf16 MFMA GEMM, 128x128 tile, fused epilogues ----------------
// MODE 0: QKV -> split/scale/bias -> qh/kh/vh [B][NH][S][HD] bf16
// MODE 1: proj -> + bias + residual -> f32 out
template <int MODE>
__global__ __launch_bounds__(256) void gemm_kernel(const unsigned short* __restrict__ A,   // [M][K]
                                                   const unsigned short* __restrict__ Bt,  // [N][K]
                                                   const float* __restrict__ bias,
                                                   unsigned short* __restrict__ qh,
                                                   unsigned short* __restrict__ kh,
                                                   unsigned short* __restrict__ vh,
                                                   const float* __restrict__ resid,
                                                   float* __restrict__ outf,
                                                   int K) {
  __shared__ unsigned short Alds[128][72];
  __shared__ unsigned short Blds[128][72];
  int tid = threadIdx.x, lane = tid & 63, w = tid >> 6;
  int li = lane & 15, g = lane >> 4;
  int wr = (w >> 1) * 64, wc = (w & 1) * 64;
  int m0 = blockIdx.y * 128, n0 = blockIdx.x * 128;
  f32x4 acc[4][4];
  for (int i = 0; i < 4; ++i)
    for (int j = 0; j < 4; ++j) acc[i][j] = (f32x4){0.f, 0.f, 0.f, 0.f};

  for (int k0 = 0; k0 < K; k0 += 64) {
    for (int i = 0; i < 4; ++i) {
      int ch = tid + i * 256;
      int r = ch >> 3, c8 = (ch & 7) * 8;
      *(int4*)&Alds[r][c8] = *(const int4*)&A[(size_t)(m0 + r) * K + k0 + c8];
      *(int4*)&Blds[r][c8] = *(const int4*)&Bt[(size_t)(n0 + r) * K + k0 + c8];
    }
    __syncthreads();
    for (int ks = 0; ks < 2; ++ks) {
      short8 af[4], bfm[4];
      for (int mi = 0; mi < 4; ++mi)
        af[mi] = *(const short8*)&Alds[wr + mi * 16 + li][ks * 32 + g * 8];
      for (int ni = 0; ni < 4; ++ni)
        bfm[ni] = *(const short8*)&Blds[wc + ni * 16 + li][ks * 32 + g * 8];
      for (int mi = 0; mi < 4; ++mi)
        for (int ni = 0; ni < 4; ++ni)
          acc[mi][ni] = __builtin_amdgcn_mfma_f32_16x16x32_bf16(af[mi], bfm[ni], acc[mi][ni], 0, 0, 0);
    }
    __syncthreads();
  }

  if (MODE == 0) {
    for (int ni = 0; ni < 4; ++ni) {
      int n = n0 + wc + ni * 16 + li;
      float bn = bias[n];
      int head = n / 192;
      int rem = n - head * 192;
      int part = rem >> 6;
      int h = rem & 63;
      unsigned short* dst = part == 0 ? qh : (part == 1 ? kh : vh);
      float mul = part == 0 ? 0.125f : 1.0f;   // 1/sqrt(hd)
      for (int mi = 0; mi < 4; ++mi)
        for (int j = 0; j < 4; ++j) {
          int m = m0 + wr + mi * 16 + g * 4 + j;
          int b = m >> 12, s = m & 4095;
          float val = (acc[mi][ni][j] + bn) * mul;
          dst[((size_t)(b * NH + head) * S_LEN + s) * HD + h] = f2bf(val);
        }
    }
  } else {
    for (int ni = 0; ni < 4; ++ni) {
      int n = n0 + wc + ni * 16 + li;
      float bn = bias[n];
      for (int mi = 0; mi < 4; ++mi)
        for (int j = 0; j < 4; ++j) {
          int m = m0 + wr + mi * 16 + g * 4 + j;
          size_t off = (size_t)m * C_DIM + n;
          outf[off] = acc[mi][ni][j] + bn + resid[off];
        }
    }
  }
}

// ---------------- flash attention: one block per (b*nh, 64-row q tile) ----------------
__global__ __launch_bounds__(256) void attn_kernel(const unsigned short* __restrict__ qh,
                                                   const unsigned short* __restrict__ kh,
                                                   const unsigned short* __restrict__ vh,
                                                   unsigned short* __restrict__ oh) {
  int bn = blockIdx.y;            // b*NH + n
  int q0 = blockIdx.x * 64;
  const unsigned short* qp = qh + (size_t)bn * S_LEN * HD;
  const unsigned short* kp = kh + (size_t)bn * S_LEN * HD;
  const unsigned short* vp = vh + (size_t)bn * S_LEN * HD;
  __shared__ unsigned short Klds[64][72];
  __shared__ unsigned short Vlds[64][72];   // transposed: [h][t]
  __shared__ unsigned short Plds[64][72];
  int tid = threadIdx.x, lane = tid & 63, w = tid >> 6;
  int li = lane & 15, g = lane >> 4;

  short8 aq[2];
  aq[0] = *(const short8*)&qp[(size_t)(q0 + w * 16 + li) * HD + g * 8];
  aq[1] = *(const short8*)&qp[(size_t)(q0 + w * 16 + li) * HD + 32 + g * 8];

  f32x4 o[4];
  for (int i = 0; i < 4; ++i) o[i] = (f32x4){0.f, 0.f, 0.f, 0.f};
  float m[4], lsum[4];
  for (int j = 0; j < 4; ++j) { m[j] = -INFINITY; lsum[j] = 0.f; }

  for (int t0 = 0; t0 < S_LEN; t0 += 64) {
    for (int i = 0; i < 2; ++i) {
      int ch = tid + i * 256;
      int r = ch >> 3, c8 = (ch & 7) * 8;
      *(int4*)&Klds[r][c8] = *(const int4*)&kp[(size_t)(t0 + r) * HD + c8];
      int4 vv = *(const int4*)&vp[(size_t)(t0 + r) * HD + c8];
      unsigned short* pv = (unsigned short*)&vv;
      for (int j = 0; j < 8; ++j) Vlds[c8 + j][r] = pv[j];
    }
    __syncthreads();

    f32x4 s[4];
    for (int i = 0; i < 4; ++i) s[i] = (f32x4){0.f, 0.f, 0.f, 0.f};
    for (int tf = 0; tf < 4; ++tf)
      for (int ks = 0; ks < 2; ++ks) {
        short8 kb = *(const short8*)&Klds[tf * 16 + li][ks * 32 + g * 8];
        s[tf] = __builtin_amdgcn_mfma_f32_16x16x32_bf16(aq[ks], kb, s[tf], 0, 0, 0);
      }

    float tmax[4];
    for (int j = 0; j < 4; ++j)
      tmax[j] = fmaxf(fmaxf(s[0][j], s[1][j]), fmaxf(s[2][j], s[3][j]));
    for (int off = 1; off < 16; off <<= 1)
      for (int j = 0; j < 4; ++j) tmax[j] = fmaxf(tmax[j], __shfl_xor(tmax[j], off));

    float corr[4], psum[4];
    for (int j = 0; j < 4; ++j) {
      float mn = fmaxf(m[j], tmax[j]);
      corr[j] = __expf(m[j] - mn);
      m[j] = mn;
      psum[j] = 0.f;
    }
    for (int tf = 0; tf < 4; ++tf)
      for (int j = 0; j < 4; ++j) {
        float p = __expf(s[tf][j] - m[j]);
        psum[j] += p;
        Plds[w * 16 + g * 4 + j][tf * 16 + li] = f2bf(p);
      }
    for (int off = 1; off < 16; off <<= 1)
      for (int j = 0; j < 4; ++j) psum[j] += __shfl_xor(psum[j], off);
    for (int j = 0; j < 4; ++j) lsum[j] = lsum[j] * corr[j] + psum[j];
    for (int i = 0; i < 4; ++i)
      for (int j = 0; j < 4; ++j) o[i][j] *= corr[j];
    __syncthreads();   // P visible (and cross-lane) before PV reads

    for (int tk = 0; tk < 2; ++tk) {
      short8 pa = *(const short8*)&Plds[w * 16 + li][tk * 32 + g * 8];
      for (int hf = 0; hf < 4; ++hf) {
        short8 vb = *(const short8*)&Vlds[hf * 16 + li][tk * 32 + g * 8];
        o[hf] = __builtin_amdgcn_mfma_f32_16x16x32_bf16(pa, vb, o[hf], 0, 0, 0);
      }
    }
    __syncthreads();   // before next tile overwrites K/V
  }

  int b = bn >> 3, n = bn & 7;
  for (int j = 0; j < 4; ++j) {
    float inv = 1.0f / lsum[j];
    int q = q0 + w * 16 + g * 4 + j;
    for (int hf = 0; hf < 4; ++hf)
      oh[((size_t)b * S_LEN + q) * C_DIM + n * HD + hf * 16 + li] = f2bf(o[hf][j] * inv);
  }
}

extern "C" void kernel_launch(void* const* d_in, const int* in_sizes, int n_in,
                              void* d_out, int out_size, void* d_ws, size_t ws_size,
                              hipStream_t stream) {
  const float* x        = (const float*)d_in[0];
  const float* gn_scale = (const float*)d_in[1];
  const float* gn_bias  = (const float*)d_in[2];
  const float* w_qkv    = (const float*)d_in[3];
  const float* b_qkv    = (const float*)d_in[4];
  const float* w_proj   = (const float*)d_in[5];
  const float* b_proj   = (const float*)d_in[6];
  float* out = (float*)d_out;

  char* ws = (char*)d_ws;
  // ws layout (bytes): all 16B-aligned, total ~44 MB
  unsigned short* q_in   = (unsigned short*)(ws);               //  8 MB [B*S][C] bf16
  unsigned short* wqkvT  = (unsigned short*)(ws + 8388608);     //  1.5 MB [1536][512]
  unsigned short* wprojT = (unsigned short*)(ws + 9961472);     //  0.5 MB [512][512]
  unsigned short* qhb    = (unsigned short*)(ws + 10485760);    //  8 MB [B][NH][S][HD]
  unsigned short* khb    = (unsigned short*)(ws + 18874368);    //  8 MB
  unsigned short* vhb    = (unsigned short*)(ws + 27262976);    //  8 MB
  unsigned short* ahb    = (unsigned short*)(ws + 35651584);    //  8 MB [B*S][C]
  float* stats           = (float*)(ws + 44040192);             //  512 B

  gn_stats_kernel<<<64, 256, 0, stream>>>(x, stats);
  gn_apply_kernel<<<4096, 256, 0, stream>>>(x, stats, gn_scale, gn_bias, q_in);
  transpose_bf16_kernel<<<dim3(48, 16), 256, 0, stream>>>(w_qkv, wqkvT, 512, 1536);
  transpose_bf16_kernel<<<dim3(16, 16), 256, 0, stream>>>(w_proj, wprojT, 512, 512);
  gemm_kernel<0><<<dim3(12, 64), 256, 0, stream>>>(q_in, wqkvT, b_qkv, qhb, khb, vhb, nullptr, nullptr, 512);
  attn_kernel<<<dim3(64, 16), 256, 0, stream>>>(qhb, khb, vhb, ahb);
  gemm_kernel<1><<<dim3(4, 64), 256, 0, stream>>>(ahb, wprojT, b_proj, nullptr, nullptr, nullptr, x, out, 512);
}

// Round 2
// 308.311 us; speedup vs baseline: 1.3295x; 1.3295x over previous
//
#include <hip/hip_runtime.h>

typedef __attribute__((ext_vector_type(8))) short short8;
typedef __attribute__((ext_vector_type(4))) float f32x4;
typedef __attribute__((ext_vector_type(16))) float f32x16;

#define S_LEN 4096
#define C_DIM 512
#define NH 8
#define HD 64
#define NG 32
#define GS 16
#define LOG2E 1.44269504088896340736f

__device__ __forceinline__ unsigned short f2bf(float f) {
  union { float f; unsigned int u; } v; v.f = f;
  unsigned int r = v.u + 0x7fffu + ((v.u >> 16) & 1u);
  return (unsigned short)(r >> 16);
}

__device__ __forceinline__ unsigned pk_bf16(float a, float b) {
  unsigned r;
  asm volatile("v_cvt_pk_bf16_f32 %0, %1, %2" : "=v"(r) : "v"(a), "v"(b));
  return r;
}

// ---------------- GroupNorm stats (4-way split over S): one block per (b,g,chunk) ----------------
__global__ __launch_bounds__(256) void gn_stats_kernel(const float* __restrict__ x,
                                                       float* __restrict__ partials) {
  int bg = blockIdx.x >> 2, chunk = blockIdx.x & 3;
  int b = bg >> 5, g = bg & 31;
  const float* xp = x + (size_t)b * S_LEN * C_DIM + g * GS;
  float s1 = 0.f, s2 = 0.f;
  for (int i = threadIdx.x; i < 1024 * 4; i += 256) {
    int s = chunk * 1024 + (i >> 2), c4 = i & 3;
    float4 v = *(const float4*)&xp[(size_t)s * C_DIM + c4 * 4];
    s1 += v.x + v.y + v.z + v.w;
    s2 += v.x * v.x + v.y * v.y + v.z * v.z + v.w * v.w;
  }
  for (int off = 1; off < 64; off <<= 1) {
    s1 += __shfl_xor(s1, off);
    s2 += __shfl_xor(s2, off);
  }
  __shared__ float r1[4], r2[4];
  int w = threadIdx.x >> 6;
  if ((threadIdx.x & 63) == 0) { r1[w] = s1; r2[w] = s2; }
  __syncthreads();
  if (threadIdx.x == 0) {
    partials[bg * 8 + chunk * 2]     = r1[0] + r1[1] + r1[2] + r1[3];
    partials[bg * 8 + chunk * 2 + 1] = r2[0] + r2[1] + r2[2] + r2[3];
  }
}

// ---------------- GroupNorm apply + bf16 cast (finalize from partials) ----------------
__global__ __launch_bounds__(256) void gn_apply_kernel(const float* __restrict__ x,
                                                       const float* __restrict__ partials,
                                                       const float* __restrict__ scale,
                                                       const float* __restrict__ bias,
                                                       unsigned short* __restrict__ out) {
  int idx = blockIdx.x * 256 + threadIdx.x;
  int e = idx * 4;
  int c = e & (C_DIM - 1);
  int bs = e >> 9;
  int b = bs >> 12;
  int grp = b * NG + (c >> 4);
  float s1 = partials[grp * 8] + partials[grp * 8 + 2] + partials[grp * 8 + 4] + partials[grp * 8 + 6];
  float s2 = partials[grp * 8 + 1] + partials[grp * 8 + 3] + partials[grp * 8 + 5] + partials[grp * 8 + 7];
  const float invN = 1.0f / (float)(S_LEN * GS);
  float mean = s1 * invN;
  float var = s2 * invN - mean * mean;
  float rstd = rsqrtf(var + 1e-6f);
  float4 v = *(const float4*)&x[e];
  ushort4 o;
  o.x = f2bf((v.x - mean) * rstd * scale[c]     + bias[c]);
  o.y = f2bf((v.y - mean) * rstd * scale[c + 1] + bias[c + 1]);
  o.z = f2bf((v.z - mean) * rstd * scale[c + 2] + bias[c + 2]);
  o.w = f2bf((v.w - mean) * rstd * scale[c + 3] + bias[c + 3]);
  *(ushort4*)&out[e] = o;
}

// ---------------- weight transpose [K][N] f32 -> [N][K] bf16 ----------------
__global__ __launch_bounds__(256) void transpose_bf16_kernel(const float* __restrict__ src,
                                                             unsigned short* __restrict__ dst,
                                                             int K, int N) {
  __shared__ float tile[32][33];
  int n0 = blockIdx.x * 32, k0 = blockIdx.y * 32;
  int c = threadIdx.x & 31, r0 = threadIdx.x >> 5;
  for (int i = 0; i < 4; ++i) {
    int r = r0 + i * 8;
    tile[r][c] = src[(size_t)(k0 + r) * N + n0 + c];
  }
  __syncthreads();
  for (int i = 0; i < 4; ++i) {
    int r = r0 + i * 8;
    dst[(size_t)(n0 + r) * K + k0 + c] = f2bf(tile[c][r]);
  }
}

// ---------------- bf16 MFMA GEMM, 128x128 tile, fused epilogues ----------------
// MODE 0: QKV -> q scaled by (1/8)*log2e -> qh [B][NH][S][HD]; kh same; V TRANSPOSED -> vh [B][NH][HD][S]
// MODE 1: proj -> + bias + residual -> f32 out
template <int MODE>
__global__ __launch_bounds__(256) void gemm_kernel(const unsigned short* __restrict__ A,   // [M][K]
                                                   const unsigned short* __restrict__ Bt,  // [N][K]
                                                   const float* __restrict__ bias,
                                                   unsigned short* __restrict__ qh,
                                                   unsigned short* __restrict__ kh,
                                                   unsigned short* __restrict__ vh,
                                                   const float* __restrict__ resid,
                                                   float* __restrict__ outf,
                                                   int K) {
  __shared__ unsigned short Alds[128][72];
  __shared__ unsigned short Blds[128][72];
  int tid = threadIdx.x, lane = tid & 63, w = tid >> 6;
  int li = lane & 15, g = lane >> 4;
  int wr = (w >> 1) * 64, wc = (w & 1) * 64;
  int m0 = blockIdx.y * 128, n0 = blockIdx.x * 128;
  f32x4 acc[4][4];
  for (int i = 0; i < 4; ++i)
    for (int j = 0; j < 4; ++j) acc[i][j] = (f32x4){0.f, 0.f, 0.f, 0.f};

  for (int k0 = 0; k0 < K; k0 += 64) {
    for (int i = 0; i < 4; ++i) {
      int ch = tid + i * 256;
      int r = ch >> 3, c8 = (ch & 7) * 8;
      *(int4*)&Alds[r][c8] = *(const int4*)&A[(size_t)(m0 + r) * K + k0 + c8];
      *(int4*)&Blds[r][c8] = *(const int4*)&Bt[(size_t)(n0 + r) * K + k0 + c8];
    }
    __syncthreads();
    for (int ks = 0; ks < 2; ++ks) {
      short8 af[4], bfm[4];
      for (int mi = 0; mi < 4; ++mi)
        af[mi] = *(const short8*)&Alds[wr + mi * 16 + li][ks * 32 + g * 8];
      for (int ni = 0; ni < 4; ++ni)
        bfm[ni] = *(const short8*)&Blds[wc + ni * 16 + li][ks * 32 + g * 8];
      for (int mi = 0; mi < 4; ++mi)
        for (int ni = 0; ni < 4; ++ni)
          acc[mi][ni] = __builtin_amdgcn_mfma_f32_16x16x32_bf16(af[mi], bfm[ni], acc[mi][ni], 0, 0, 0);
    }
    __syncthreads();
  }

  if (MODE == 0) {
    for (int ni = 0; ni < 4; ++ni) {
      int n = n0 + wc + ni * 16 + li;
      float bn = bias[n];
      int head = n / 192;
      int rem = n - head * 192;
      int part = rem >> 6;
      int h = rem & 63;
      unsigned short* dst = part == 0 ? qh : (part == 1 ? kh : vh);
      float mul = part == 0 ? 0.125f * LOG2E : 1.0f;   // fold 1/sqrt(hd) and log2(e) into q
      for (int mi = 0; mi < 4; ++mi)
        for (int j = 0; j < 4; ++j) {
          int m = m0 + wr + mi * 16 + g * 4 + j;
          int b = m >> 12, s = m & 4095;
          float val = (acc[mi][ni][j] + bn) * mul;
          size_t idx;
          if (part == 2) idx = ((size_t)(b * NH + head) * HD + h) * S_LEN + s;          // V^T: [hd][S]
          else           idx = ((size_t)(b * NH + head) * S_LEN + s) * HD + h;          // Q/K: [S][hd]
          dst[idx] = f2bf(val);
        }
    }
  } else {
    for (int ni = 0; ni < 4; ++ni) {
      int n = n0 + wc + ni * 16 + li;
      float bn = bias[n];
      for (int mi = 0; mi < 4; ++mi)
        for (int j = 0; j < 4; ++j) {
          int m = m0 + wr + mi * 16 + g * 4 + j;
          size_t off = (size_t)m * C_DIM + n;
          outf[off] = acc[mi][ni][j] + bn + resid[off];
        }
    }
  }
}

// ---------------- attention: swapped QK^T, in-register softmax, no LDS, no barriers ----------------
// Each wave owns 32 q-rows. S^T = mfma32x32(A=K, B=Qs): lane holds P^T col q=lane&31,
// rows t=(reg&3)+8*(reg>>2)+4*hi (+16*regblk). PV: o^T = mfma32x32(A=V^T, B=P^T-frag).
__global__ __launch_bounds__(256, 2) void attn_kernel(const unsigned short* __restrict__ qh,
                                                      const unsigned short* __restrict__ kh,
                                                      const unsigned short* __restrict__ vt,
                                                      unsigned short* __restrict__ ob) {
  int bn = blockIdx.y;
  int lane = threadIdx.x & 63, wv = threadIdx.x >> 6;
  int r32 = lane & 31, hi = lane >> 5;
  int q0 = blockIdx.x * 128 + wv * 32;
  const unsigned short* qp = qh + (size_t)bn * S_LEN * HD;
  const unsigned short* kp = kh + (size_t)bn * S_LEN * HD;
  const unsigned short* vp = vt + (size_t)bn * HD * S_LEN;

  short8 qf[4];
#pragma unroll
  for (int ks = 0; ks < 4; ++ks)
    qf[ks] = *(const short8*)&qp[(size_t)(q0 + r32) * HD + ks * 16 + hi * 8];

  f32x16 o0, o1;
#pragma unroll
  for (int i = 0; i < 16; ++i) { o0[i] = 0.f; o1[i] = 0.f; }
  float mrun = -INFINITY, lrun = 0.f;

  for (int t0 = 0; t0 < S_LEN; t0 += 32) {
    // issue K and V fragment loads together (V latency hides under QK+softmax)
    short8 kf[4], vf[4];
#pragma unroll
    for (int ks = 0; ks < 4; ++ks)
      kf[ks] = *(const short8*)&kp[(size_t)(t0 + r32) * HD + ks * 16 + hi * 8];
#pragma unroll
    for (int kk = 0; kk < 2; ++kk)
#pragma unroll
      for (int hf = 0; hf < 2; ++hf)
        vf[kk * 2 + hf] = *(const short8*)&vp[(size_t)(hf * 32 + r32) * S_LEN + t0 + kk * 16 + hi * 8];

    f32x16 s;
#pragma unroll
    for (int i = 0; i < 16; ++i) s[i] = 0.f;
#pragma unroll
    for (int ks = 0; ks < 4; ++ks)
      s = __builtin_amdgcn_mfma_f32_32x32x16_bf16(kf[ks], qf[ks], s, 0, 0, 0);

    // row (over t) max: 15 in-lane + 1 cross-half
    float tm = s[0];
#pragma unroll
    for (int i = 1; i < 16; ++i) tm = fmaxf(tm, s[i]);
    tm = fmaxf(tm, __shfl_xor(tm, 32));

    // defer-max (T13): only rescale when the max grew by > 8 (in log2 domain)
    if (!__all(tm - mrun <= 8.0f)) {
      float mnew = fmaxf(mrun, tm);
      float corr = exp2f(mrun - mnew);
      lrun *= corr;
#pragma unroll
      for (int i = 0; i < 16; ++i) { o0[i] *= corr; o1[i] *= corr; }
      mrun = mnew;
    }

    float pv[16];
    float ps = 0.f;
#pragma unroll
    for (int i = 0; i < 16; ++i) { pv[i] = exp2f(s[i] - mrun); ps += pv[i]; }
    lrun += ps + __shfl_xor(ps, 32);

    // pack to bf16 pairs; exchange across lane-half pair to build PV B-fragments
    unsigned pk[8], sx[8];
#pragma unroll
    for (int g2 = 0; g2 < 8; ++g2) pk[g2] = pk_bf16(pv[2 * g2], pv[2 * g2 + 1]);
#pragma unroll
    for (int g2 = 0; g2 < 8; ++g2) sx[g2] = __shfl_xor(pk[g2], 32);

    // F0 covers t=0..15: lane needs t=8*hi..8*hi+7; F1 covers t=16..31
    union { unsigned u[4]; short8 v; } F0, F1;
    F0.u[0] = hi ? sx[2] : pk[0];  F0.u[1] = hi ? sx[3] : pk[1];
    F0.u[2] = hi ? pk[2] : sx[0];  F0.u[3] = hi ? pk[3] : sx[1];
    F1.u[0] = hi ? sx[6] : pk[4];  F1.u[1] = hi ? sx[7] : pk[5];
    F1.u[2] = hi ? pk[6] : sx[4];  F1.u[3] = hi ? pk[7] : sx[5];

    o0 = __builtin_amdgcn_mfma_f32_32x32x16_bf16(vf[0], F0.v, o0, 0, 0, 0);
    o1 = __builtin_amdgcn_mfma_f32_32x32x16_bf16(vf[1], F0.v, o1, 0, 0, 0);
    o0 = __builtin_amdgcn_mfma_f32_32x32x16_bf16(vf[2], F1.v, o0, 0, 0, 0);
    o1 = __builtin_amdgcn_mfma_f32_32x32x16_bf16(vf[3], F1.v, o1, 0, 0, 0);
  }

  float inv = 1.0f / lrun;
  int b = bn >> 3, n = bn & 7;
  size_t base = ((size_t)(b * S_LEN + q0 + r32)) * C_DIM + n * HD;
#pragma unroll
  for (int r = 0; r < 16; ++r) {
    int hrow = (r & 3) + 8 * (r >> 2) + 4 * hi;
    ob[base + hrow]      = f2bf(o0[r] * inv);
    ob[base + 32 + hrow] = f2bf(o1[r] * inv);
  }
}

extern "C" void kernel_launch(void* const* d_in, const int* in_sizes, int n_in,
                              void* d_out, int out_size, void* d_ws, size_t ws_size,
                              hipStream_t stream) {
  const float* x        = (const float*)d_in[0];
  const float* gn_scale = (const float*)d_in[1];
  const float* gn_bias  = (const float*)d_in[2];
  const float* w_qkv    = (const float*)d_in[3];
  const float* b_qkv    = (const float*)d_in[4];
  const float* w_proj   = (const float*)d_in[5];
  const float* b_proj   = (const float*)d_in[6];
  float* out = (float*)d_out;

  char* ws = (char*)d_ws;
  unsigned short* q_in   = (unsigned short*)(ws);               //  8 MB [B*S][C] bf16
  unsigned short* wqkvT  = (unsigned short*)(ws + 8388608);     //  1.5 MB [1536][512]
  unsigned short* wprojT = (unsigned short*)(ws + 9961472);     //  0.5 MB [512][512]
  unsigned short* qhb    = (unsigned short*)(ws + 10485760);    //  8 MB [B][NH][S][HD]
  unsigned short* khb    = (unsigned short*)(ws + 18874368);    //  8 MB [B][NH][S][HD]
  unsigned short* vtb    = (unsigned short*)(ws + 27262976);    //  8 MB [B][NH][HD][S]  (V^T)
  unsigned short* ahb    = (unsigned short*)(ws + 35651584);    //  8 MB [B*S][C]
  float* partials        = (float*)(ws + 44040192);             //  2 KB [64][4][2]

  gn_stats_kernel<<<256, 256, 0, stream>>>(x, partials);
  gn_apply_kernel<<<4096, 256, 0, stream>>>(x, partials, gn_scale, gn_bias, q_in);
  transpose_bf16_kernel<<<dim3(48, 16), 256, 0, stream>>>(w_qkv, wqkvT, 512, 1536);
  transpose_bf16_kernel<<<dim3(16, 16), 256, 0, stream>>>(w_proj, wprojT, 512, 512);
  gemm_kernel<0><<<dim3(12, 64), 256, 0, stream>>>(q_in, wqkvT, b_qkv, qhb, khb, vtb, nullptr, nullptr, 512);
  attn_kernel<<<dim3(32, 16), 256, 0, stream>>>(qhb, khb, vtb, ahb);
  gemm_kernel<1><<<dim3(4, 64), 256, 0, stream>>>(ahb, wprojT, b_proj, nullptr, nullptr, nullptr, x, out, 512);
}

// Round 3
// 298.087 us; speedup vs baseline: 1.3751x; 1.0343x over previous
//
#include <hip/hip_runtime.h>

typedef __attribute__((ext_vector_type(8))) short short8;
typedef __attribute__((ext_vector_type(4))) float f32x4;
typedef __attribute__((ext_vector_type(16))) float f32x16;

#define S_LEN 4096
#define C_DIM 512
#define NH 8
#define HD 64
#define NG 32
#define GS 16
#define LOG2E 1.44269504088896340736f

__device__ __forceinline__ unsigned short f2bf(float f) {
  union { float f; unsigned int u; } v; v.f = f;
  unsigned int r = v.u + 0x7fffu + ((v.u >> 16) & 1u);
  return (unsigned short)(r >> 16);
}

__device__ __forceinline__ unsigned pk_bf16(float a, float b) {
  unsigned r;
  asm volatile("v_cvt_pk_bf16_f32 %0, %1, %2" : "=v"(r) : "v"(a), "v"(b));
  return r;
}

// ---------------- GroupNorm stats (4-way split over S): one block per (b,g,chunk) ----------------
__global__ __launch_bounds__(256) void gn_stats_kernel(const float* __restrict__ x,
                                                       float* __restrict__ partials) {
  int bg = blockIdx.x >> 2, chunk = blockIdx.x & 3;
  int b = bg >> 5, g = bg & 31;
  const float* xp = x + (size_t)b * S_LEN * C_DIM + g * GS;
  float s1 = 0.f, s2 = 0.f;
  for (int i = threadIdx.x; i < 1024 * 4; i += 256) {
    int s = chunk * 1024 + (i >> 2), c4 = i & 3;
    float4 v = *(const float4*)&xp[(size_t)s * C_DIM + c4 * 4];
    s1 += v.x + v.y + v.z + v.w;
    s2 += v.x * v.x + v.y * v.y + v.z * v.z + v.w * v.w;
  }
  for (int off = 1; off < 64; off <<= 1) {
    s1 += __shfl_xor(s1, off);
    s2 += __shfl_xor(s2, off);
  }
  __shared__ float r1[4], r2[4];
  int w = threadIdx.x >> 6;
  if ((threadIdx.x & 63) == 0) { r1[w] = s1; r2[w] = s2; }
  __syncthreads();
  if (threadIdx.x == 0) {
    partials[bg * 8 + chunk * 2]     = r1[0] + r1[1] + r1[2] + r1[3];
    partials[bg * 8 + chunk * 2 + 1] = r2[0] + r2[1] + r2[2] + r2[3];
  }
}

// ---------------- GroupNorm apply + bf16 cast (finalize from partials) ----------------
__global__ __launch_bounds__(256) void gn_apply_kernel(const float* __restrict__ x,
                                                       const float* __restrict__ partials,
                                                       const float* __restrict__ scale,
                                                       const float* __restrict__ bias,
                                                       unsigned short* __restrict__ out) {
  int idx = blockIdx.x * 256 + threadIdx.x;
  int e = idx * 4;
  int c = e & (C_DIM - 1);
  int bs = e >> 9;
  int b = bs >> 12;
  int grp = b * NG + (c >> 4);
  float s1 = partials[grp * 8] + partials[grp * 8 + 2] + partials[grp * 8 + 4] + partials[grp * 8 + 6];
  float s2 = partials[grp * 8 + 1] + partials[grp * 8 + 3] + partials[grp * 8 + 5] + partials[grp * 8 + 7];
  const float invN = 1.0f / (float)(S_LEN * GS);
  float mean = s1 * invN;
  float var = s2 * invN - mean * mean;
  float rstd = rsqrtf(var + 1e-6f);
  float4 v = *(const float4*)&x[e];
  ushort4 o;
  o.x = f2bf((v.x - mean) * rstd * scale[c]     + bias[c]);
  o.y = f2bf((v.y - mean) * rstd * scale[c + 1] + bias[c + 1]);
  o.z = f2bf((v.z - mean) * rstd * scale[c + 2] + bias[c + 2]);
  o.w = f2bf((v.w - mean) * rstd * scale[c + 3] + bias[c + 3]);
  *(ushort4*)&out[e] = o;
}

// ---------------- weight transpose [K][N] f32 -> [N][K] bf16 ----------------
__global__ __launch_bounds__(256) void transpose_bf16_kernel(const float* __restrict__ src,
                                                             unsigned short* __restrict__ dst,
                                                             int K, int N) {
  __shared__ float tile[32][33];
  int n0 = blockIdx.x * 32, k0 = blockIdx.y * 32;
  int c = threadIdx.x & 31, r0 = threadIdx.x >> 5;
  for (int i = 0; i < 4; ++i) {
    int r = r0 + i * 8;
    tile[r][c] = src[(size_t)(k0 + r) * N + n0 + c];
  }
  __syncthreads();
  for (int i = 0; i < 4; ++i) {
    int r = r0 + i * 8;
    dst[(size_t)(n0 + r) * K + k0 + c] = f2bf(tile[c][r]);
  }
}

// ---------------- bf16 MFMA GEMM, 128x128 tile, fused epilogues ----------------
// MODE 0: QKV -> q scaled by (1/8)*log2e -> qh [B][NH][S][HD]; kh same; V TRANSPOSED -> vh [B][NH][HD][S]
// MODE 1: proj -> + bias + residual -> f32 out
template <int MODE>
__global__ __launch_bounds__(256) void gemm_kernel(const unsigned short* __restrict__ A,   // [M][K]
                                                   const unsigned short* __restrict__ Bt,  // [N][K]
                                                   const float* __restrict__ bias,
                                                   unsigned short* __restrict__ qh,
                                                   unsigned short* __restrict__ kh,
                                                   unsigned short* __restrict__ vh,
                                                   const float* __restrict__ resid,
                                                   float* __restrict__ outf,
                                                   int K) {
  __shared__ unsigned short Alds[128][72];
  __shared__ unsigned short Blds[128][72];
  int tid = threadIdx.x, lane = tid & 63, w = tid >> 6;
  int li = lane & 15, g = lane >> 4;
  int wr = (w >> 1) * 64, wc = (w & 1) * 64;
  int m0 = blockIdx.y * 128, n0 = blockIdx.x * 128;
  f32x4 acc[4][4];
  for (int i = 0; i < 4; ++i)
    for (int j = 0; j < 4; ++j) acc[i][j] = (f32x4){0.f, 0.f, 0.f, 0.f};

  for (int k0 = 0; k0 < K; k0 += 64) {
    for (int i = 0; i < 4; ++i) {
      int ch = tid + i * 256;
      int r = ch >> 3, c8 = (ch & 7) * 8;
      *(int4*)&Alds[r][c8] = *(const int4*)&A[(size_t)(m0 + r) * K + k0 + c8];
      *(int4*)&Blds[r][c8] = *(const int4*)&Bt[(size_t)(n0 + r) * K + k0 + c8];
    }
    __syncthreads();
    for (int ks = 0; ks < 2; ++ks) {
      short8 af[4], bfm[4];
      for (int mi = 0; mi < 4; ++mi)
        af[mi] = *(const short8*)&Alds[wr + mi * 16 + li][ks * 32 + g * 8];
      for (int ni = 0; ni < 4; ++ni)
        bfm[ni] = *(const short8*)&Blds[wc + ni * 16 + li][ks * 32 + g * 8];
      for (int mi = 0; mi < 4; ++mi)
        for (int ni = 0; ni < 4; ++ni)
          acc[mi][ni] = __builtin_amdgcn_mfma_f32_16x16x32_bf16(af[mi], bfm[ni], acc[mi][ni], 0, 0, 0);
    }
    __syncthreads();
  }

  if (MODE == 0) {
    for (int ni = 0; ni < 4; ++ni) {
      int n = n0 + wc + ni * 16 + li;
      float bn = bias[n];
      int head = n / 192;
      int rem = n - head * 192;
      int part = rem >> 6;
      int h = rem & 63;
      unsigned short* dst = part == 0 ? qh : (part == 1 ? kh : vh);
      float mul = part == 0 ? 0.125f * LOG2E : 1.0f;   // fold 1/sqrt(hd) and log2(e) into q
      for (int mi = 0; mi < 4; ++mi)
        for (int j = 0; j < 4; ++j) {
          int m = m0 + wr + mi * 16 + g * 4 + j;
          int b = m >> 12, s = m & 4095;
          float val = (acc[mi][ni][j] + bn) * mul;
          size_t idx;
          if (part == 2) idx = ((size_t)(b * NH + head) * HD + h) * S_LEN + s;          // V^T: [hd][S]
          else           idx = ((size_t)(b * NH + head) * S_LEN + s) * HD + h;          // Q/K: [S][hd]
          dst[idx] = f2bf(val);
        }
    }
  } else {
    for (int ni = 0; ni < 4; ++ni) {
      int n = n0 + wc + ni * 16 + li;
      float bn = bias[n];
      for (int mi = 0; mi < 4; ++mi)
        for (int j = 0; j < 4; ++j) {
          int m = m0 + wr + mi * 16 + g * 4 + j;
          size_t off = (size_t)m * C_DIM + n;
          outf[off] = acc[mi][ni][j] + bn + resid[off];
        }
    }
  }
}

// ---------------- attention: swapped QK^T, in-register softmax, 2-deep pipelined ----------------
// Each wave owns 32 q-rows. Pipeline: issue QK[t+1] mfma, prefetch K/V[t+2], softmax[t] VALU, PV[t].
__global__ __launch_bounds__(256, 2) void attn_kernel(const unsigned short* __restrict__ qh,
                                                      const unsigned short* __restrict__ kh,
                                                      const unsigned short* __restrict__ vt,
                                                      unsigned short* __restrict__ ob) {
  int bn = blockIdx.y;
  int lane = threadIdx.x & 63, wv = threadIdx.x >> 6;
  int r32 = lane & 31, hi = lane >> 5;
  int q0 = blockIdx.x * 128 + wv * 32;
  const unsigned short* qp = qh + (size_t)bn * S_LEN * HD;
  const unsigned short* kp = kh + (size_t)bn * S_LEN * HD;
  const unsigned short* vp = vt + (size_t)bn * HD * S_LEN;

  short8 qf[4];
#pragma unroll
  for (int ks = 0; ks < 4; ++ks)
    qf[ks] = *(const short8*)&qp[(size_t)(q0 + r32) * HD + ks * 16 + hi * 8];

  f32x16 o0, o1;
#pragma unroll
  for (int i = 0; i < 16; ++i) { o0[i] = 0.f; o1[i] = 0.f; }
  float mrun = -INFINITY, lrun = 0.f;

  short8 kA[4], kB[4], vA[4], vB[4];

  auto loadK = [&](short8 (&kf)[4], int t0) {
#pragma unroll
    for (int ks = 0; ks < 4; ++ks)
      kf[ks] = *(const short8*)&kp[(size_t)(t0 + r32) * HD + ks * 16 + hi * 8];
  };
  auto loadV = [&](short8 (&vf)[4], int t0) {
#pragma unroll
    for (int kk = 0; kk < 2; ++kk)
#pragma unroll
      for (int hf = 0; hf < 2; ++hf)
        vf[kk * 2 + hf] = *(const short8*)&vp[(size_t)(hf * 32 + r32) * S_LEN + t0 + kk * 16 + hi * 8];
  };
  auto qk = [&](const short8 (&kf)[4]) {
    f32x16 s;
#pragma unroll
    for (int i = 0; i < 16; ++i) s[i] = 0.f;
#pragma unroll
    for (int ks = 0; ks < 4; ++ks)
      s = __builtin_amdgcn_mfma_f32_32x32x16_bf16(kf[ks], qf[ks], s, 0, 0, 0);
    return s;
  };
  // softmax (in-register, deferred-max) + PV accumulate for one 32-t tile
  auto smpv = [&](f32x16& s, const short8 (&vf)[4]) {
    float a0 = fmaxf(fmaxf(s[0], s[1]), s[2]);
    float a1 = fmaxf(fmaxf(s[3], s[4]), s[5]);
    float a2 = fmaxf(fmaxf(s[6], s[7]), s[8]);
    float a3 = fmaxf(fmaxf(s[9], s[10]), s[11]);
    float a4 = fmaxf(fmaxf(s[12], s[13]), s[14]);
    float tm = fmaxf(fmaxf(fmaxf(a0, a1), fmaxf(a2, a3)), fmaxf(a4, s[15]));
    tm = fmaxf(tm, __shfl_xor(tm, 32));
    if (!__all(tm - mrun <= 8.0f)) {            // defer-max (T13)
      float mnew = fmaxf(mrun, tm);
      float corr = exp2f(mrun - mnew);
      lrun *= corr;
#pragma unroll
      for (int i = 0; i < 16; ++i) { o0[i] *= corr; o1[i] *= corr; }
      mrun = mnew;
    }
    float p[16];
    float ps = 0.f;
#pragma unroll
    for (int i = 0; i < 16; ++i) { p[i] = exp2f(s[i] - mrun); ps += p[i]; }
    lrun += ps + __shfl_xor(ps, 32);

    unsigned pk[8], sx[8];
#pragma unroll
    for (int g2 = 0; g2 < 8; ++g2) pk[g2] = pk_bf16(p[2 * g2], p[2 * g2 + 1]);
#pragma unroll
    for (int g2 = 0; g2 < 8; ++g2) sx[g2] = __shfl_xor(pk[g2], 32);

    union { unsigned u[4]; short8 v; } F0, F1;
    F0.u[0] = hi ? sx[2] : pk[0];  F0.u[1] = hi ? sx[3] : pk[1];
    F0.u[2] = hi ? pk[2] : sx[0];  F0.u[3] = hi ? pk[3] : sx[1];
    F1.u[0] = hi ? sx[6] : pk[4];  F1.u[1] = hi ? sx[7] : pk[5];
    F1.u[2] = hi ? pk[6] : sx[4];  F1.u[3] = hi ? pk[7] : sx[5];

    o0 = __builtin_amdgcn_mfma_f32_32x32x16_bf16(vf[0], F0.v, o0, 0, 0, 0);
    o1 = __builtin_amdgcn_mfma_f32_32x32x16_bf16(vf[1], F0.v, o1, 0, 0, 0);
    o0 = __builtin_amdgcn_mfma_f32_32x32x16_bf16(vf[2], F1.v, o0, 0, 0, 0);
    o1 = __builtin_amdgcn_mfma_f32_32x32x16_bf16(vf[3], F1.v, o1, 0, 0, 0);
  };

  // prologue: tiles 0 (A) and 1 (B) in flight; scores for tile 0
  loadK(kA, 0);  loadV(vA, 0);
  loadK(kB, 32); loadV(vB, 32);
  f32x16 sA = qk(kA);
  f32x16 sB;

  // steady state: 126 of 128 tiles, ping-pong A(even)/B(odd)
  for (int tt = 0; tt < 126; tt += 2) {
    sB = qk(kB);                  // scores tile tt+1 (matrix pipe)
    loadK(kA, (tt + 2) * 32);     // prefetch K tile tt+2
    smpv(sA, vA);                 // softmax+PV tile tt (VALU overlaps)
    loadV(vA, (tt + 2) * 32);     // prefetch V tile tt+2

    sA = qk(kA);                  // scores tile tt+2
    loadK(kB, (tt + 3) * 32);     // prefetch K tile tt+3
    smpv(sB, vB);                 // softmax+PV tile tt+1
    loadV(vB, (tt + 3) * 32);     // prefetch V tile tt+3
  }
  // tail: tiles 126 (A) and 127 (B)
  sB = qk(kB);
  smpv(sA, vA);
  smpv(sB, vB);

  float inv = 1.0f / lrun;
  int b = bn >> 3, n = bn & 7;
  size_t base = ((size_t)(b * S_LEN + q0 + r32)) * C_DIM + n * HD;
#pragma unroll
  for (int r = 0; r < 16; ++r) {
    int hrow = (r & 3) + 8 * (r >> 2) + 4 * hi;
    ob[base + hrow]      = f2bf(o0[r] * inv);
    ob[base + 32 + hrow] = f2bf(o1[r] * inv);
  }
}

extern "C" void kernel_launch(void* const* d_in, const int* in_sizes, int n_in,
                              void* d_out, int out_size, void* d_ws, size_t ws_size,
                              hipStream_t stream) {
  const float* x        = (const float*)d_in[0];
  const float* gn_scale = (const float*)d_in[1];
  const float* gn_bias  = (const float*)d_in[2];
  const float* w_qkv    = (const float*)d_in[3];
  const float* b_qkv    = (const float*)d_in[4];
  const float* w_proj   = (const float*)d_in[5];
  const float* b_proj   = (const float*)d_in[6];
  float* out = (float*)d_out;

  char* ws = (char*)d_ws;
  unsigned short* q_in   = (unsigned short*)(ws);               //  8 MB [B*S][C] bf16
  unsigned short* wqkvT  = (unsigned short*)(ws + 8388608);     //  1.5 MB [1536][512]
  unsigned short* wprojT = (unsigned short*)(ws + 9961472);     //  0.5 MB [512][512]
  unsigned short* qhb    = (unsigned short*)(ws + 10485760);    //  8 MB [B][NH][S][HD]
  unsigned short* khb    = (unsigned short*)(ws + 18874368);    //  8 MB [B][NH][S][HD]
  unsigned short* vtb    = (unsigned short*)(ws + 27262976);    //  8 MB [B][NH][HD][S]  (V^T)
  unsigned short* ahb    = (unsigned short*)(ws + 35651584);    //  8 MB [B*S][C]
  float* partials        = (float*)(ws + 44040192);             //  2 KB [64][4][2]

  gn_stats_kernel<<<256, 256, 0, stream>>>(x, partials);
  gn_apply_kernel<<<4096, 256, 0, stream>>>(x, partials, gn_scale, gn_bias, q_in);
  transpose_bf16_kernel<<<dim3(48, 16), 256, 0, stream>>>(w_qkv, wqkvT, 512, 1536);
  transpose_bf16_kernel<<<dim3(16, 16), 256, 0, stream>>>(w_proj, wprojT, 512, 512);
  gemm_kernel<0><<<dim3(12, 64), 256, 0, stream>>>(q_in, wqkvT, b_qkv, qhb, khb, vtb, nullptr, nullptr, 512);
  attn_kernel<<<dim3(32, 16), 256, 0, stream>>>(qhb, khb, vtb, ahb);
  gemm_kernel<1><<<dim3(4, 64), 256, 0, stream>>>(ahb, wprojT, b_proj, nullptr, nullptr, nullptr, x, out, 512);
}